// Round 1
// baseline (942.815 us; speedup 1.0000x reference)
//
#include <hip/hip_runtime.h>
#include <hip/hip_bf16.h>
#include <math.h>

#define BQ 2
#define NV 6
#define CIN 64
#define HF 32
#define WF 56
#define ND 32
#define BEVC 128
#define BEVH 128
#define BEVW 128
#define NPIX (HF*WF)     // 1792
#define BV (BQ*NV)       // 12
#define EXT 20.0f
#define BN_S 0.99999500003749937f

__device__ __forceinline__ float gelu(float x) {
    return 0.5f * x * (1.0f + erff(x * 0.70710678118654752f));
}

// ---------------- Kernel 1: 3x3 conv 64->64, *BN_S, gelu. NCHW in/out ----------------
// block (56, 8), grid (BV, HF, CIN/8)
__global__ void k_conv1(const float* __restrict__ fm, const float* __restrict__ w,
                        const float* __restrict__ bias, float* __restrict__ out) {
    int x  = threadIdx.x;
    int co = blockIdx.z * 8 + threadIdx.y;
    int y  = blockIdx.y;
    int bv = blockIdx.x;
    const float* in0 = fm + (size_t)bv * CIN * NPIX;
    float acc = bias[co];
    for (int ci = 0; ci < CIN; ++ci) {
        const float* ip = in0 + ci * NPIX;
        const float* wp = w + (co * CIN + ci) * 9;
        #pragma unroll
        for (int dy = 0; dy < 3; ++dy) {
            int yy = y + dy - 1;
            if (yy < 0 || yy >= HF) continue;
            #pragma unroll
            for (int dx = 0; dx < 3; ++dx) {
                int xx = x + dx - 1;
                if (xx < 0 || xx >= WF) continue;
                acc += wp[dy * 3 + dx] * ip[yy * WF + xx];
            }
        }
    }
    acc *= BN_S;
    out[((size_t)bv * CIN + co) * NPIX + y * WF + x] = gelu(acc);
}

// ---------------- Kernel 2: 1x1 conv 64->32 + softmax over 32. out [p][d] ----------------
// block 256, grid BV*NPIX/256 = 84
__global__ void k_depth(const float* __restrict__ h, const float* __restrict__ w,
                        const float* __restrict__ bias, float* __restrict__ dp) {
    __shared__ float wl[ND * CIN];
    __shared__ float bl[ND];
    for (int i = threadIdx.x; i < ND * CIN; i += 256) wl[i] = w[i];
    if (threadIdx.x < ND) bl[threadIdx.x] = bias[threadIdx.x];
    __syncthreads();
    int g = blockIdx.x * 256 + threadIdx.x;
    if (g >= BV * NPIX) return;
    int bv = g / NPIX, pix = g % NPIX;
    float hv[CIN];
    const float* hp = h + (size_t)bv * CIN * NPIX + pix;
    #pragma unroll
    for (int ci = 0; ci < CIN; ci++) hv[ci] = hp[ci * NPIX];
    float o[ND];
    float mx = -1e30f;
    #pragma unroll
    for (int d = 0; d < ND; d++) {
        float acc = bl[d];
        #pragma unroll
        for (int ci = 0; ci < CIN; ci++) acc += wl[d * CIN + ci] * hv[ci];
        o[d] = acc;
        mx = fmaxf(mx, acc);
    }
    float s = 0.f;
    #pragma unroll
    for (int d = 0; d < ND; d++) { o[d] = expf(o[d] - mx); s += o[d]; }
    float inv = 1.0f / s;
    float* op = dp + (size_t)g * ND;
    #pragma unroll
    for (int d = 0; d < ND; d++) op[d] = o[d] * inv;
}

// ---------------- Kernel 3: 1x1 conv 64->128, *BN_S, gelu. out NHWC-ish [p][co] ----------------
// block 256, grid BV*NPIX*BEVC/256 = 10752
__global__ void k_fp(const float* __restrict__ fm, const float* __restrict__ w,
                     const float* __restrict__ bias, float* __restrict__ fp) {
    __shared__ float wl[CIN * BEVC]; // [ci][co]
    __shared__ float bl[BEVC];
    for (int i = threadIdx.x; i < CIN * BEVC; i += 256) {
        int co = i / CIN, ci = i % CIN;
        wl[ci * BEVC + co] = w[i];
    }
    if (threadIdx.x < BEVC) bl[threadIdx.x] = bias[threadIdx.x];
    __syncthreads();
    size_t g = (size_t)blockIdx.x * 256 + threadIdx.x;
    int co = (int)(g & (BEVC - 1));
    int p  = (int)(g >> 7);          // bv*NPIX + pix
    int bv = p / NPIX;
    int pix = p % NPIX;
    const float* ip = fm + (size_t)bv * CIN * NPIX + pix;
    float acc = bl[co];
    #pragma unroll
    for (int ci = 0; ci < CIN; ci++) acc += wl[ci * BEVC + co] * ip[(size_t)ci * NPIX];
    acc *= BN_S;
    fp[g] = gelu(acc);
}

// ---------------- Kernel 4: scatter to BEV (NHWC). block 128 (=channels), grid BV*NPIX ----------------
__global__ void k_scatter(const float* __restrict__ fp, const float* __restrict__ dp,
                          const float* __restrict__ Km, const float* __restrict__ Tm,
                          const float* __restrict__ trust, const float* __restrict__ depths,
                          float* __restrict__ bev) {
    int blk = blockIdx.x;
    int bv = blk / NPIX, pix = blk % NPIX;
    int b  = bv / NV;
    int py = pix / WF, px = pix % WF;
    int c  = threadIdx.x;

    const float* Kp = Km + bv * 9;
    float a = Kp[0], bb = Kp[1], cc = Kp[2];
    float d = Kp[3], e  = Kp[4], f  = Kp[5];
    float g = Kp[6], hh = Kp[7], ii = Kp[8];
    float A  = e * ii - f * hh;
    float Bm = -(d * ii - f * g);
    float Cm = d * hh - e * g;
    float det = a * A + bb * Bm + cc * Cm;
    float invd = 1.0f / det;
    float i00 = A * invd,                  i01 = -(bb * ii - cc * hh) * invd, i02 = (bb * f - cc * e) * invd;
    float i10 = Bm * invd,                 i11 = (a * ii - cc * g) * invd,    i12 = -(a * f - cc * d) * invd;
    float i20 = Cm * invd,                 i21 = -(a * hh - bb * g) * invd,   i22 = (a * e - bb * d) * invd;

    float fx = (float)px, fy = (float)py;
    float r0 = i00 * fx + i01 * fy + i02;
    float r1 = i10 * fx + i11 * fy + i12;
    float r2 = i20 * fx + i21 * fy + i22;

    const float* Tp = Tm + bv * 16;
    float R00 = Tp[0], R01 = Tp[1], R02 = Tp[2], t0 = Tp[3];
    float R10 = Tp[4], R11 = Tp[5], R12 = Tp[6], t1 = Tp[7];
    float tw = trust[bv];

    float fpv = fp[(size_t)blk * BEVC + c] * tw;
    const float* dpp = dp + (size_t)blk * ND;
    float* bevb = bev + (size_t)b * BEVH * BEVW * BEVC;

    for (int di = 0; di < ND; ++di) {
        float dep = depths[di];
        float xe = R00 * (r0 * dep) + R01 * (r1 * dep) + R02 * (r2 * dep) + t0;
        float ye = R10 * (r0 * dep) + R11 * (r1 * dep) + R12 * (r2 * dep) + t1;
        int col = (int)((xe + EXT) / (2.0f * EXT) * (float)(BEVW - 1));
        int row = (int)((ye + EXT) / (2.0f * EXT) * (float)(BEVH - 1));
        if (col >= 0 && col < BEVW && row >= 0 && row < BEVH) {
            float v = fpv * dpp[di];
            atomicAdd(&bevb[((size_t)row * BEVW + col) * BEVC + c], v);
        }
    }
}

// ---------------- weight transpose: w[co][ci][k] -> wT[k][ci][co] ----------------
__global__ void k_wT(const float* __restrict__ w, float* __restrict__ wT) {
    int i = blockIdx.x * 256 + threadIdx.x;
    if (i >= BEVC * BEVC * 9) return;
    int co = i / (BEVC * 9);
    int rem = i % (BEVC * 9);
    int ci = rem / 9, k = rem % 9;
    wT[((size_t)k * BEVC + ci) * BEVC + co] = w[i];
}

// ---------------- Kernel 5/6: 3x3 conv 128->128 NHWC, *BN_S, gelu ----------------
// block 128 (co). Tile: 2 rows (y) x 8 cols (x). grid (BEVW/8, BEVH/2, B)
#define TX 8
#define TY 2
__global__ void k_bevconv(const float* __restrict__ in, const float* __restrict__ wT,
                          const float* __restrict__ bias, float* __restrict__ out) {
    __shared__ float lds[(TY + 2) * (TX + 2) * BEVC];
    int co = threadIdx.x;
    int x0 = blockIdx.x * TX;
    int y0 = blockIdx.y * TY;
    int b  = blockIdx.z;
    const float* inb = in + (size_t)b * BEVH * BEVW * BEVC;

    for (int i = threadIdx.x; i < (TY + 2) * (TX + 2) * BEVC; i += 128) {
        int r   = i / ((TX + 2) * BEVC);
        int rem = i % ((TX + 2) * BEVC);
        int xx  = rem / BEVC;
        int ci  = rem % BEVC;
        int gy = y0 + r - 1, gx = x0 + xx - 1;
        float v = 0.f;
        if (gy >= 0 && gy < BEVH && gx >= 0 && gx < BEVW)
            v = inb[((size_t)gy * BEVW + gx) * BEVC + ci];
        lds[i] = v;
    }
    __syncthreads();

    float acc[TY][TX];
    float bi = bias[co];
    #pragma unroll
    for (int yy = 0; yy < TY; yy++)
        #pragma unroll
        for (int t = 0; t < TX; t++) acc[yy][t] = bi;

    for (int ci = 0; ci < BEVC; ci++) {
        float wv[9];
        #pragma unroll
        for (int k = 0; k < 9; k++) wv[k] = wT[((size_t)k * BEVC + ci) * BEVC + co];
        float vv[TY + 2][TX + 2];
        #pragma unroll
        for (int r = 0; r < TY + 2; r++)
            #pragma unroll
            for (int xx = 0; xx < TX + 2; xx++)
                vv[r][xx] = lds[(r * (TX + 2) + xx) * BEVC + ci];
        #pragma unroll
        for (int yy = 0; yy < TY; yy++)
            #pragma unroll
            for (int r = 0; r < 3; r++)
                #pragma unroll
                for (int dx = 0; dx < 3; dx++) {
                    float wvv = wv[r * 3 + dx];
                    #pragma unroll
                    for (int t = 0; t < TX; t++)
                        acc[yy][t] += wvv * vv[yy + r][t + dx];
                }
    }

    #pragma unroll
    for (int yy = 0; yy < TY; yy++)
        #pragma unroll
        for (int t = 0; t < TX; t++) {
            float v = gelu(acc[yy][t] * BN_S);
            out[(((size_t)b * BEVH + (y0 + yy)) * BEVW + (x0 + t)) * BEVC + co] = v;
        }
}

// ---------------- NHWC -> NCHW transpose for final output ----------------
// block 256 (64 c-lanes x 4 rows); per (b,y), 2x2 tiles of 64x64 over (x,c)
__global__ void k_to_nchw(const float* __restrict__ in, float* __restrict__ out) {
    __shared__ float t[64][65];
    int b = blockIdx.z;
    int y = blockIdx.y;
    int xt = (blockIdx.x & 1) * 64;
    int ct = (blockIdx.x >> 1) * 64;
    int lc = threadIdx.x & 63;
    int lr = threadIdx.x >> 6;
    #pragma unroll
    for (int i = 0; i < 16; i++) {
        int xi = lr + i * 4;
        t[xi][lc] = in[(((size_t)b * BEVH + y) * BEVW + xt + xi) * BEVC + ct + lc];
    }
    __syncthreads();
    #pragma unroll
    for (int i = 0; i < 16; i++) {
        int ci = lr + i * 4;
        out[(((size_t)b * BEVC + ct + ci) * BEVH + y) * BEVW + xt + lc] = t[lc][ci];
    }
}

extern "C" void kernel_launch(void* const* d_in, const int* in_sizes, int n_in,
                              void* d_out, int out_size, void* d_ws, size_t ws_size,
                              hipStream_t stream) {
    const float* feat_maps = (const float*)d_in[0];
    const float* Km        = (const float*)d_in[1];
    const float* Tm        = (const float*)d_in[2];
    const float* trust     = (const float*)d_in[3];
    const float* depths    = (const float*)d_in[4];
    const float* dh_w1     = (const float*)d_in[5];
    const float* dh_b1     = (const float*)d_in[6];
    const float* dh_w2     = (const float*)d_in[7];
    const float* dh_b2     = (const float*)d_in[8];
    const float* fp_w      = (const float*)d_in[9];
    const float* fp_b      = (const float*)d_in[10];
    const float* br_w1     = (const float*)d_in[11];
    const float* br_b1     = (const float*)d_in[12];
    const float* br_w2     = (const float*)d_in[13];
    const float* br_b2     = (const float*)d_in[14];
    float* out = (float*)d_out;

    float* ws  = (float*)d_ws;
    float* h1  = ws;                       // 12*64*1792   = 1,376,256
    float* dpb = h1 + (size_t)BV * CIN * NPIX;      // 12*1792*32   =   688,128
    float* fpb = dpb + (size_t)BV * NPIX * ND;      // 12*1792*128  = 2,752,512
    float* bev = fpb + (size_t)BV * NPIX * BEVC;    // 2*16384*128  = 4,194,304
    float* h2  = bev + (size_t)BQ * BEVH * BEVW * BEVC;
    float* o2  = h2 + (size_t)BQ * BEVH * BEVW * BEVC;
    float* wT1 = o2 + (size_t)BQ * BEVH * BEVW * BEVC;
    float* wT2 = wT1 + (size_t)BEVC * BEVC * 9;

    // transpose BEV conv weights
    k_wT<<<dim3((BEVC * BEVC * 9 + 255) / 256), dim3(256), 0, stream>>>(br_w1, wT1);
    k_wT<<<dim3((BEVC * BEVC * 9 + 255) / 256), dim3(256), 0, stream>>>(br_w2, wT2);

    // depth-head conv1 + gelu
    k_conv1<<<dim3(BV, HF, CIN / 8), dim3(WF, 8), 0, stream>>>(feat_maps, dh_w1, dh_b1, h1);

    // depth probs
    k_depth<<<dim3(BV * NPIX / 256), dim3(256), 0, stream>>>(h1, dh_w2, dh_b2, dpb);

    // feature projection
    k_fp<<<dim3(BV * NPIX * BEVC / 256), dim3(256), 0, stream>>>(feat_maps, fp_w, fp_b, fpb);

    // zero BEV accumulator, scatter
    hipMemsetAsync(bev, 0, (size_t)BQ * BEVH * BEVW * BEVC * sizeof(float), stream);
    k_scatter<<<dim3(BV * NPIX), dim3(BEVC), 0, stream>>>(fpb, dpb, Km, Tm, trust, depths, bev);

    // BEV refinement convs
    k_bevconv<<<dim3(BEVW / TX, BEVH / TY, BQ), dim3(BEVC), 0, stream>>>(bev, wT1, br_b1, h2);
    k_bevconv<<<dim3(BEVW / TX, BEVH / TY, BQ), dim3(BEVC), 0, stream>>>(h2, wT2, br_b2, o2);

    // NHWC -> NCHW
    k_to_nchw<<<dim3(4, BEVH, BQ), dim3(256), 0, stream>>>(o2, out);
}

// Round 2
// 815.248 us; speedup vs baseline: 1.1565x; 1.1565x over previous
//
#include <hip/hip_runtime.h>
#include <hip/hip_bf16.h>
#include <math.h>

#define BQ 2
#define NV 6
#define CIN 64
#define HF 32
#define WF 56
#define ND 32
#define BEVC 128
#define BEVH 128
#define BEVW 128
#define NPIX (HF*WF)     // 1792
#define BV (BQ*NV)       // 12
#define EXT 20.0f
#define BN_S 0.99999500003749937f

__device__ __forceinline__ float gelu(float x) {
    return 0.5f * x * (1.0f + erff(x * 0.70710678118654752f));
}

// ---------------- Kernel 1: 3x3 conv 64->64, *BN_S, gelu. NCHW in/out ----------------
// thread = one pixel, computes COG output channels. Weights via wave-uniform (scalar) loads.
// block 256, grid (BV*NPIX/256 = 84, CIN/COG = 4)
#define COG 16
__global__ void k_conv1(const float* __restrict__ fm, const float* __restrict__ w,
                        const float* __restrict__ bias, float* __restrict__ out) {
    int g   = blockIdx.x * 256 + threadIdx.x;
    int co0 = blockIdx.y * COG;
    int bv  = g / NPIX, pix = g % NPIX;
    int py  = pix / WF, px = pix % WF;
    const float* in0 = fm + (size_t)bv * CIN * NPIX + py * WF + px;

    bool ym[3], xm[3];
    #pragma unroll
    for (int d = 0; d < 3; d++) {
        ym[d] = (unsigned)(py + d - 1) < (unsigned)HF;
        xm[d] = (unsigned)(px + d - 1) < (unsigned)WF;
    }

    float acc[COG];
    #pragma unroll
    for (int c = 0; c < COG; c++) acc[c] = bias[co0 + c];

    for (int ci = 0; ci < CIN; ci++) {
        const float* ip = in0 + ci * NPIX;
        float v[9];
        #pragma unroll
        for (int dy = 0; dy < 3; dy++)
            #pragma unroll
            for (int dx = 0; dx < 3; dx++)
                v[dy * 3 + dx] = (ym[dy] && xm[dx]) ? ip[(dy - 1) * WF + (dx - 1)] : 0.0f;
        const float* wp = w + ((size_t)co0 * CIN + ci) * 9;  // wave-uniform -> s_load
        #pragma unroll
        for (int c = 0; c < COG; c++)
            #pragma unroll
            for (int k = 0; k < 9; k++)
                acc[c] += wp[(size_t)c * CIN * 9 + k] * v[k];
    }

    float* op = out + (size_t)bv * CIN * NPIX + (size_t)co0 * NPIX + pix;
    #pragma unroll
    for (int c = 0; c < COG; c++) op[(size_t)c * NPIX] = gelu(acc[c] * BN_S);
}

// ---------------- Kernel 2: 1x1 conv 64->32 + softmax over 32. out [p][d] ----------------
// block 256, grid BV*NPIX/256 = 84
__global__ void k_depth(const float* __restrict__ h, const float* __restrict__ w,
                        const float* __restrict__ bias, float* __restrict__ dp) {
    __shared__ float wl[ND * CIN];
    __shared__ float bl[ND];
    for (int i = threadIdx.x; i < ND * CIN; i += 256) wl[i] = w[i];
    if (threadIdx.x < ND) bl[threadIdx.x] = bias[threadIdx.x];
    __syncthreads();
    int g = blockIdx.x * 256 + threadIdx.x;
    if (g >= BV * NPIX) return;
    int bv = g / NPIX, pix = g % NPIX;
    float hv[CIN];
    const float* hp = h + (size_t)bv * CIN * NPIX + pix;
    #pragma unroll
    for (int ci = 0; ci < CIN; ci++) hv[ci] = hp[ci * NPIX];
    float o[ND];
    float mx = -1e30f;
    #pragma unroll
    for (int d = 0; d < ND; d++) {
        float acc = bl[d];
        #pragma unroll
        for (int ci = 0; ci < CIN; ci++) acc += wl[d * CIN + ci] * hv[ci];
        o[d] = acc;
        mx = fmaxf(mx, acc);
    }
    float s = 0.f;
    #pragma unroll
    for (int d = 0; d < ND; d++) { o[d] = expf(o[d] - mx); s += o[d]; }
    float inv = 1.0f / s;
    float* op = dp + (size_t)g * ND;
    #pragma unroll
    for (int d = 0; d < ND; d++) op[d] = o[d] * inv;
}

// ---------------- Kernel 3: 1x1 conv 64->128, *BN_S, gelu. out [p][co] ----------------
// block 256, grid BV*NPIX*BEVC/256 = 10752
__global__ void k_fp(const float* __restrict__ fm, const float* __restrict__ w,
                     const float* __restrict__ bias, float* __restrict__ fp) {
    __shared__ float wl[CIN * BEVC]; // [ci][co]
    __shared__ float bl[BEVC];
    for (int i = threadIdx.x; i < CIN * BEVC; i += 256) {
        int co = i / CIN, ci = i % CIN;
        wl[ci * BEVC + co] = w[i];
    }
    if (threadIdx.x < BEVC) bl[threadIdx.x] = bias[threadIdx.x];
    __syncthreads();
    size_t g = (size_t)blockIdx.x * 256 + threadIdx.x;
    int co = (int)(g & (BEVC - 1));
    int p  = (int)(g >> 7);          // bv*NPIX + pix
    int bv = p / NPIX;
    int pix = p % NPIX;
    const float* ip = fm + (size_t)bv * CIN * NPIX + pix;
    float acc = bl[co];
    #pragma unroll
    for (int ci = 0; ci < CIN; ci++) acc += wl[ci * BEVC + co] * ip[(size_t)ci * NPIX];
    acc *= BN_S;
    fp[g] = gelu(acc);
}

// ---------------- Kernel 4: scatter to BEV (NHWC). block 128 (=channels), grid BV*NPIX ----------------
__global__ void k_scatter(const float* __restrict__ fp, const float* __restrict__ dp,
                          const float* __restrict__ Km, const float* __restrict__ Tm,
                          const float* __restrict__ trust, const float* __restrict__ depths,
                          float* __restrict__ bev) {
    int blk = blockIdx.x;
    int bv = blk / NPIX, pix = blk % NPIX;
    int b  = bv / NV;
    int py = pix / WF, px = pix % WF;
    int c  = threadIdx.x;

    const float* Kp = Km + bv * 9;
    float a = Kp[0], bb = Kp[1], cc = Kp[2];
    float d = Kp[3], e  = Kp[4], f  = Kp[5];
    float g = Kp[6], hh = Kp[7], ii = Kp[8];
    float A  = e * ii - f * hh;
    float Bm = -(d * ii - f * g);
    float Cm = d * hh - e * g;
    float det = a * A + bb * Bm + cc * Cm;
    float invd = 1.0f / det;
    float i00 = A * invd,                  i01 = -(bb * ii - cc * hh) * invd, i02 = (bb * f - cc * e) * invd;
    float i10 = Bm * invd,                 i11 = (a * ii - cc * g) * invd,    i12 = -(a * f - cc * d) * invd;
    float i20 = Cm * invd,                 i21 = -(a * hh - bb * g) * invd,   i22 = (a * e - bb * d) * invd;

    float fx = (float)px, fy = (float)py;
    float r0 = i00 * fx + i01 * fy + i02;
    float r1 = i10 * fx + i11 * fy + i12;
    float r2 = i20 * fx + i21 * fy + i22;

    const float* Tp = Tm + bv * 16;
    float R00 = Tp[0], R01 = Tp[1], R02 = Tp[2], t0 = Tp[3];
    float R10 = Tp[4], R11 = Tp[5], R12 = Tp[6], t1 = Tp[7];
    float tw = trust[bv];

    float fpv = fp[(size_t)blk * BEVC + c] * tw;
    const float* dpp = dp + (size_t)blk * ND;
    float* bevb = bev + (size_t)b * BEVH * BEVW * BEVC;

    for (int di = 0; di < ND; ++di) {
        float dep = depths[di];
        float xe = R00 * (r0 * dep) + R01 * (r1 * dep) + R02 * (r2 * dep) + t0;
        float ye = R10 * (r0 * dep) + R11 * (r1 * dep) + R12 * (r2 * dep) + t1;
        int col = (int)((xe + EXT) / (2.0f * EXT) * (float)(BEVW - 1));
        int row = (int)((ye + EXT) / (2.0f * EXT) * (float)(BEVH - 1));
        if (col >= 0 && col < BEVW && row >= 0 && row < BEVH) {
            float v = fpv * dpp[di];
            atomicAdd(&bevb[((size_t)row * BEVW + col) * BEVC + c], v);
        }
    }
}

// ---------------- weight transpose: w[co][ci][k] -> wT[ci][k][co] ----------------
__global__ void k_wT(const float* __restrict__ w, float* __restrict__ wT) {
    int i = blockIdx.x * 256 + threadIdx.x;
    if (i >= BEVC * BEVC * 9) return;
    int co = i / (BEVC * 9);
    int rem = i % (BEVC * 9);
    int ci = rem / 9, k = rem % 9;
    wT[((size_t)ci * 9 + k) * BEVC + co] = w[i];
}

// ---------------- Kernel 5/6: 3x3 conv 128->128 NHWC, *BN_S, gelu ----------------
// block 128 (co). Tile: TY rows x TX cols. LDS layout [ci][row][x] padded, broadcast b128 reads.
#define TX 8
#define TY 4
#define LROW 12              // padded row stride (48B, 16B-aligned)
#define LCI  ((TY + 2) * LROW) // 72 floats per ci
__global__ void k_bevconv(const float* __restrict__ in, const float* __restrict__ wT,
                          const float* __restrict__ bias, float* __restrict__ out) {
    __shared__ float lds[BEVC * LCI]; // 128*72*4 = 36864 B
    int co = threadIdx.x;
    int x0 = blockIdx.x * TX;
    int y0 = blockIdx.y * TY;
    int b  = blockIdx.z;
    const float* inb = in + (size_t)b * BEVH * BEVW * BEVC;

    // stage: lane handles channel ci = lane for all (TY+2) x (TX+2) positions
    {
        int ci = threadIdx.x;
        #pragma unroll
        for (int r = 0; r < TY + 2; r++) {
            int gy = y0 + r - 1;
            bool yv = (unsigned)gy < (unsigned)BEVH;
            #pragma unroll
            for (int xx = 0; xx < TX + 2; xx++) {
                int gx = x0 + xx - 1;
                float v = 0.f;
                if (yv && (unsigned)gx < (unsigned)BEVW)
                    v = inb[((size_t)gy * BEVW + gx) * BEVC + ci];
                lds[ci * LCI + r * LROW + xx] = v;
            }
        }
    }
    __syncthreads();

    float acc[TY][TX];
    float bi = bias[co];
    #pragma unroll
    for (int yy = 0; yy < TY; yy++)
        #pragma unroll
        for (int t = 0; t < TX; t++) acc[yy][t] = bi;

    for (int ci = 0; ci < BEVC; ci++) {
        float wv[9];
        #pragma unroll
        for (int k = 0; k < 9; k++) wv[k] = wT[((size_t)ci * 9 + k) * BEVC + co];
        #pragma unroll
        for (int ir = 0; ir < TY + 2; ir++) {
            const float4* lp = (const float4*)&lds[ci * LCI + ir * LROW];
            float4 q0 = lp[0], q1 = lp[1], q2 = lp[2];
            float rowv[12] = {q0.x, q0.y, q0.z, q0.w, q1.x, q1.y, q1.z, q1.w,
                              q2.x, q2.y, q2.z, q2.w};
            #pragma unroll
            for (int yy = 0; yy < TY; yy++) {
                int r = ir - yy;
                if (r < 0 || r > 2) continue;
                #pragma unroll
                for (int dx = 0; dx < 3; dx++) {
                    float wvv = wv[r * 3 + dx];
                    #pragma unroll
                    for (int t = 0; t < TX; t++)
                        acc[yy][t] += wvv * rowv[t + dx];
                }
            }
        }
    }

    #pragma unroll
    for (int yy = 0; yy < TY; yy++)
        #pragma unroll
        for (int t = 0; t < TX; t++) {
            float v = gelu(acc[yy][t] * BN_S);
            out[(((size_t)b * BEVH + (y0 + yy)) * BEVW + (x0 + t)) * BEVC + co] = v;
        }
}

// ---------------- NHWC -> NCHW transpose for final output ----------------
__global__ void k_to_nchw(const float* __restrict__ in, float* __restrict__ out) {
    __shared__ float t[64][65];
    int b = blockIdx.z;
    int y = blockIdx.y;
    int xt = (blockIdx.x & 1) * 64;
    int ct = (blockIdx.x >> 1) * 64;
    int lc = threadIdx.x & 63;
    int lr = threadIdx.x >> 6;
    #pragma unroll
    for (int i = 0; i < 16; i++) {
        int xi = lr + i * 4;
        t[xi][lc] = in[(((size_t)b * BEVH + y) * BEVW + xt + xi) * BEVC + ct + lc];
    }
    __syncthreads();
    #pragma unroll
    for (int i = 0; i < 16; i++) {
        int ci = lr + i * 4;
        out[(((size_t)b * BEVC + ct + ci) * BEVH + y) * BEVW + xt + lc] = t[lc][ci];
    }
}

extern "C" void kernel_launch(void* const* d_in, const int* in_sizes, int n_in,
                              void* d_out, int out_size, void* d_ws, size_t ws_size,
                              hipStream_t stream) {
    const float* feat_maps = (const float*)d_in[0];
    const float* Km        = (const float*)d_in[1];
    const float* Tm        = (const float*)d_in[2];
    const float* trust     = (const float*)d_in[3];
    const float* depths    = (const float*)d_in[4];
    const float* dh_w1     = (const float*)d_in[5];
    const float* dh_b1     = (const float*)d_in[6];
    const float* dh_w2     = (const float*)d_in[7];
    const float* dh_b2     = (const float*)d_in[8];
    const float* fp_w      = (const float*)d_in[9];
    const float* fp_b      = (const float*)d_in[10];
    const float* br_w1     = (const float*)d_in[11];
    const float* br_b1     = (const float*)d_in[12];
    const float* br_w2     = (const float*)d_in[13];
    const float* br_b2     = (const float*)d_in[14];
    float* out = (float*)d_out;

    float* ws  = (float*)d_ws;
    float* h1  = ws;                                // 12*64*1792
    float* dpb = h1 + (size_t)BV * CIN * NPIX;      // 12*1792*32
    float* fpb = dpb + (size_t)BV * NPIX * ND;      // 12*1792*128
    float* bev = fpb + (size_t)BV * NPIX * BEVC;    // 2*16384*128
    float* h2  = bev + (size_t)BQ * BEVH * BEVW * BEVC;
    float* o2  = h2 + (size_t)BQ * BEVH * BEVW * BEVC;
    float* wT1 = o2 + (size_t)BQ * BEVH * BEVW * BEVC;
    float* wT2 = wT1 + (size_t)BEVC * BEVC * 9;

    // transpose BEV conv weights -> [ci][k][co]
    k_wT<<<dim3((BEVC * BEVC * 9 + 255) / 256), dim3(256), 0, stream>>>(br_w1, wT1);
    k_wT<<<dim3((BEVC * BEVC * 9 + 255) / 256), dim3(256), 0, stream>>>(br_w2, wT2);

    // depth-head conv1 + gelu
    k_conv1<<<dim3(BV * NPIX / 256, CIN / COG), dim3(256), 0, stream>>>(feat_maps, dh_w1, dh_b1, h1);

    // depth probs
    k_depth<<<dim3(BV * NPIX / 256), dim3(256), 0, stream>>>(h1, dh_w2, dh_b2, dpb);

    // feature projection
    k_fp<<<dim3(BV * NPIX * BEVC / 256), dim3(256), 0, stream>>>(feat_maps, fp_w, fp_b, fpb);

    // zero BEV accumulator, scatter
    hipMemsetAsync(bev, 0, (size_t)BQ * BEVH * BEVW * BEVC * sizeof(float), stream);
    k_scatter<<<dim3(BV * NPIX), dim3(BEVC), 0, stream>>>(fpb, dpb, Km, Tm, trust, depths, bev);

    // BEV refinement convs
    k_bevconv<<<dim3(BEVW / TX, BEVH / TY, BQ), dim3(BEVC), 0, stream>>>(bev, wT1, br_b1, h2);
    k_bevconv<<<dim3(BEVW / TX, BEVH / TY, BQ), dim3(BEVC), 0, stream>>>(h2, wT2, br_b2, o2);

    // NHWC -> NCHW
    k_to_nchw<<<dim3(4, BEVH, BQ), dim3(256), 0, stream>>>(o2, out);
}

// Round 3
// 538.284 us; speedup vs baseline: 1.7515x; 1.5145x over previous
//
#include <hip/hip_runtime.h>
#include <hip/hip_bf16.h>
#include <math.h>

#define BQ 2
#define NV 6
#define CIN 64
#define HF 32
#define WF 56
#define ND 32
#define BEVC 128
#define BEVH 128
#define BEVW 128
#define NPIX (HF*WF)     // 1792
#define BV (BQ*NV)       // 12
#define EXT 20.0f
#define BN_S 0.99999500003749937f

typedef short bf16x8 __attribute__((ext_vector_type(8)));
typedef float f32x4 __attribute__((ext_vector_type(4)));

__device__ __forceinline__ float gelu(float x) {
    return 0.5f * x * (1.0f + erff(x * 0.70710678118654752f));
}

__device__ __forceinline__ unsigned short f2bf(float x) {
    union { float f; unsigned u; } v; v.f = x;
    unsigned r = v.u + 0x7FFFu + ((v.u >> 16) & 1u);
    return (unsigned short)(r >> 16);
}

// ---------------- Kernel 1: 3x3 conv 64->64, *BN_S, gelu. NCHW in/out ----------------
#define COG 16
__global__ void k_conv1(const float* __restrict__ fm, const float* __restrict__ w,
                        const float* __restrict__ bias, float* __restrict__ out) {
    int g   = blockIdx.x * 256 + threadIdx.x;
    int co0 = blockIdx.y * COG;
    int bv  = g / NPIX, pix = g % NPIX;
    int py  = pix / WF, px = pix % WF;
    const float* in0 = fm + (size_t)bv * CIN * NPIX + py * WF + px;

    bool ym[3], xm[3];
    #pragma unroll
    for (int d = 0; d < 3; d++) {
        ym[d] = (unsigned)(py + d - 1) < (unsigned)HF;
        xm[d] = (unsigned)(px + d - 1) < (unsigned)WF;
    }

    float acc[COG];
    #pragma unroll
    for (int c = 0; c < COG; c++) acc[c] = bias[co0 + c];

    for (int ci = 0; ci < CIN; ci++) {
        const float* ip = in0 + ci * NPIX;
        float v[9];
        #pragma unroll
        for (int dy = 0; dy < 3; dy++)
            #pragma unroll
            for (int dx = 0; dx < 3; dx++)
                v[dy * 3 + dx] = (ym[dy] && xm[dx]) ? ip[(dy - 1) * WF + (dx - 1)] : 0.0f;
        const float* wp = w + ((size_t)co0 * CIN + ci) * 9;  // wave-uniform -> s_load
        #pragma unroll
        for (int c = 0; c < COG; c++)
            #pragma unroll
            for (int k = 0; k < 9; k++)
                acc[c] += wp[(size_t)c * CIN * 9 + k] * v[k];
    }

    float* op = out + (size_t)bv * CIN * NPIX + (size_t)co0 * NPIX + pix;
    #pragma unroll
    for (int c = 0; c < COG; c++) op[(size_t)c * NPIX] = gelu(acc[c] * BN_S);
}

// ---------------- Kernel 2: 1x1 conv 64->32 + softmax over 32. out [p][d] ----------------
__global__ void k_depth(const float* __restrict__ h, const float* __restrict__ w,
                        const float* __restrict__ bias, float* __restrict__ dp) {
    __shared__ float wl[ND * CIN];
    __shared__ float bl[ND];
    for (int i = threadIdx.x; i < ND * CIN; i += 256) wl[i] = w[i];
    if (threadIdx.x < ND) bl[threadIdx.x] = bias[threadIdx.x];
    __syncthreads();
    int g = blockIdx.x * 256 + threadIdx.x;
    if (g >= BV * NPIX) return;
    int bv = g / NPIX, pix = g % NPIX;
    float hv[CIN];
    const float* hp = h + (size_t)bv * CIN * NPIX + pix;
    #pragma unroll
    for (int ci = 0; ci < CIN; ci++) hv[ci] = hp[ci * NPIX];
    float o[ND];
    float mx = -1e30f;
    #pragma unroll
    for (int d = 0; d < ND; d++) {
        float acc = bl[d];
        #pragma unroll
        for (int ci = 0; ci < CIN; ci++) acc += wl[d * CIN + ci] * hv[ci];
        o[d] = acc;
        mx = fmaxf(mx, acc);
    }
    float s = 0.f;
    #pragma unroll
    for (int d = 0; d < ND; d++) { o[d] = expf(o[d] - mx); s += o[d]; }
    float inv = 1.0f / s;
    float* op = dp + (size_t)g * ND;
    #pragma unroll
    for (int d = 0; d < ND; d++) op[d] = o[d] * inv;
}

// ---------------- Kernel 3: 1x1 conv 64->128, *BN_S, gelu. out [p][co] ----------------
__global__ void k_fp(const float* __restrict__ fm, const float* __restrict__ w,
                     const float* __restrict__ bias, float* __restrict__ fp) {
    __shared__ float wl[CIN * BEVC]; // [ci][co]
    __shared__ float bl[BEVC];
    for (int i = threadIdx.x; i < CIN * BEVC; i += 256) {
        int co = i / CIN, ci = i % CIN;
        wl[ci * BEVC + co] = w[i];
    }
    if (threadIdx.x < BEVC) bl[threadIdx.x] = bias[threadIdx.x];
    __syncthreads();
    size_t g = (size_t)blockIdx.x * 256 + threadIdx.x;
    int co = (int)(g & (BEVC - 1));
    int p  = (int)(g >> 7);
    int bv = p / NPIX;
    int pix = p % NPIX;
    const float* ip = fm + (size_t)bv * CIN * NPIX + pix;
    float acc = bl[co];
    #pragma unroll
    for (int ci = 0; ci < CIN; ci++) acc += wl[ci * BEVC + co] * ip[(size_t)ci * NPIX];
    acc *= BN_S;
    fp[g] = gelu(acc);
}

// ---------------- Kernel 4: scatter to BEV (NHWC). block 128, grid BV*NPIX ----------------
__global__ void k_scatter(const float* __restrict__ fp, const float* __restrict__ dp,
                          const float* __restrict__ Km, const float* __restrict__ Tm,
                          const float* __restrict__ trust, const float* __restrict__ depths,
                          float* __restrict__ bev) {
    int blk = blockIdx.x;
    int bv = blk / NPIX, pix = blk % NPIX;
    int b  = bv / NV;
    int py = pix / WF, px = pix % WF;
    int c  = threadIdx.x;

    const float* Kp = Km + bv * 9;
    float a = Kp[0], bb = Kp[1], cc = Kp[2];
    float d = Kp[3], e  = Kp[4], f  = Kp[5];
    float g = Kp[6], hh = Kp[7], ii = Kp[8];
    float A  = e * ii - f * hh;
    float Bm = -(d * ii - f * g);
    float Cm = d * hh - e * g;
    float det = a * A + bb * Bm + cc * Cm;
    float invd = 1.0f / det;
    float i00 = A * invd,  i01 = -(bb * ii - cc * hh) * invd, i02 = (bb * f - cc * e) * invd;
    float i10 = Bm * invd, i11 = (a * ii - cc * g) * invd,    i12 = -(a * f - cc * d) * invd;
    float i20 = Cm * invd, i21 = -(a * hh - bb * g) * invd,   i22 = (a * e - bb * d) * invd;

    float fx = (float)px, fy = (float)py;
    float r0 = i00 * fx + i01 * fy + i02;
    float r1 = i10 * fx + i11 * fy + i12;
    float r2 = i20 * fx + i21 * fy + i22;

    const float* Tp = Tm + bv * 16;
    float R00 = Tp[0], R01 = Tp[1], R02 = Tp[2], t0 = Tp[3];
    float R10 = Tp[4], R11 = Tp[5], R12 = Tp[6], t1 = Tp[7];
    float tw = trust[bv];

    float fpv = fp[(size_t)blk * BEVC + c] * tw;
    const float* dpp = dp + (size_t)blk * ND;
    float* bevb = bev + (size_t)b * BEVH * BEVW * BEVC;

    for (int di = 0; di < ND; ++di) {
        float dep = depths[di];
        float xe = R00 * (r0 * dep) + R01 * (r1 * dep) + R02 * (r2 * dep) + t0;
        float ye = R10 * (r0 * dep) + R11 * (r1 * dep) + R12 * (r2 * dep) + t1;
        int col = (int)((xe + EXT) / (2.0f * EXT) * (float)(BEVW - 1));
        int row = (int)((ye + EXT) / (2.0f * EXT) * (float)(BEVH - 1));
        if (col >= 0 && col < BEVW && row >= 0 && row < BEVH) {
            float v = fpv * dpp[di];
            atomicAdd(&bevb[((size_t)row * BEVW + col) * BEVC + c], v);
        }
    }
}

// ---------------- weight prep: w[co][ci][3][3] fp32 -> fragment-linear bf16 ----------------
// layout [kpos(9)][kstep(4)][ntile(8)][lane(64)][e(8)]
// value = W[co=ntile*16+(lane&15)][ci=kstep*32+(lane>>4)*8+e][kpos]
__global__ void k_wprep(const float* __restrict__ w, unsigned short* __restrict__ wf) {
    int i = blockIdx.x * 256 + threadIdx.x;
    if (i >= 9 * 4 * 8 * 64 * 8) return;
    int e     = i & 7;
    int lane  = (i >> 3) & 63;
    int ntile = (i >> 9) & 7;
    int kstep = (i >> 12) & 3;
    int kpos  = i >> 14;
    int co = ntile * 16 + (lane & 15);
    int ci = kstep * 32 + ((lane >> 4) << 3) + e;
    wf[i] = f2bf(w[((size_t)co * BEVC + ci) * 9 + kpos]);
}

// ---------------- Kernel 5/6: 3x3 conv 128->128 NHWC via MFMA bf16 ----------------
// block 256 (4 waves). Tile: 16 x-cols (M) x 4 y-rows x 128 co (N). wave w: co [w*32, w*32+32)
#define TX2 16
#define TY2 4
#define HALO_W 18
#define HALO_H 6
#define HP (HALO_W*HALO_H)   // 108

__device__ __forceinline__ int swz(int pix, int off) {
    return pix * 256 + (off ^ ((pix & 7) << 4));
}

template<int TI_BF, int TO_BF>
__global__ void k_bevconv(const void* __restrict__ in_, const unsigned short* __restrict__ wfrag,
                          const float* __restrict__ bias, void* __restrict__ out_) {
    __shared__ char ldsb[HP * 256];   // 27648 B: [pix(108)][ci(128) bf16], XOR-swizzled
    int x0 = blockIdx.x * TX2;
    int y0 = blockIdx.y * TY2;
    int b  = blockIdx.z;

    // ---- stage halo to LDS as bf16 (swizzled) ----
    for (int t = threadIdx.x; t < HP * 16; t += 256) {
        int pix = t >> 4, oct = t & 15;
        int r = pix / HALO_W, c = pix % HALO_W;
        int gy = y0 + r - 1, gx = x0 + c - 1;
        int4 w4 = {0, 0, 0, 0};
        if ((unsigned)gy < (unsigned)BEVH && (unsigned)gx < (unsigned)BEVW) {
            size_t base = ((size_t)(b * BEVH + gy) * BEVW + gx) * BEVC + oct * 8;
            if (TI_BF) {
                w4 = *(const int4*)((const unsigned short*)in_ + base);
            } else {
                const float* p = (const float*)in_ + base;
                float4 f0 = ((const float4*)p)[0];
                float4 f1 = ((const float4*)p)[1];
                w4.x = f2bf(f0.x) | ((int)f2bf(f0.y) << 16);
                w4.y = f2bf(f0.z) | ((int)f2bf(f0.w) << 16);
                w4.z = f2bf(f1.x) | ((int)f2bf(f1.y) << 16);
                w4.w = f2bf(f1.z) | ((int)f2bf(f1.w) << 16);
            }
        }
        *(int4*)(ldsb + swz(pix, oct * 16)) = w4;
    }
    __syncthreads();

    int wave = threadIdx.x >> 6;
    int lane = threadIdx.x & 63;
    int xx   = lane & 15;     // M-row = x position within tile
    int kgrp = lane >> 4;     // 0..3

    const bf16x8* wv = (const bf16x8*)wfrag;

    f32x4 acc[TY2][2];
    {
        float b0 = bias[wave * 32 + (lane & 15)];
        float b1 = bias[wave * 32 + 16 + (lane & 15)];
        #pragma unroll
        for (int m = 0; m < TY2; m++) {
            acc[m][0] = (f32x4){b0, b0, b0, b0};
            acc[m][1] = (f32x4){b1, b1, b1, b1};
        }
    }

    for (int kpos = 0; kpos < 9; kpos++) {
        int dy = kpos / 3, dx = kpos % 3;
        #pragma unroll
        for (int kstep = 0; kstep < 4; kstep++) {
            bf16x8 bf0 = wv[((kpos * 4 + kstep) * 8 + wave * 2 + 0) * 64 + lane];
            bf16x8 bf1 = wv[((kpos * 4 + kstep) * 8 + wave * 2 + 1) * 64 + lane];
            #pragma unroll
            for (int m = 0; m < TY2; m++) {
                bf16x8 a = *(const bf16x8*)(ldsb + swz((m + dy) * HALO_W + xx + dx,
                                                       kstep * 64 + kgrp * 16));
                acc[m][0] = __builtin_amdgcn_mfma_f32_16x16x32_bf16(a, bf0, acc[m][0], 0, 0, 0);
                acc[m][1] = __builtin_amdgcn_mfma_f32_16x16x32_bf16(a, bf1, acc[m][1], 0, 0, 0);
            }
        }
    }

    // ---- epilogue: C/D col=lane&15 (co), row=kgrp*4+r (x position) ----
    #pragma unroll
    for (int m = 0; m < TY2; m++) {
        int gy = y0 + m;
        #pragma unroll
        for (int n = 0; n < 2; n++) {
            int co = wave * 32 + n * 16 + (lane & 15);
            #pragma unroll
            for (int r = 0; r < 4; r++) {
                int gx = x0 + kgrp * 4 + r;
                float v = gelu(acc[m][n][r] * BN_S);
                size_t oi = ((size_t)(b * BEVH + gy) * BEVW + gx) * BEVC + co;
                if (TO_BF) ((unsigned short*)out_)[oi] = f2bf(v);
                else       ((float*)out_)[oi] = v;
            }
        }
    }
}

// ---------------- NHWC -> NCHW transpose for final output ----------------
__global__ void k_to_nchw(const float* __restrict__ in, float* __restrict__ out) {
    __shared__ float t[64][65];
    int b = blockIdx.z;
    int y = blockIdx.y;
    int xt = (blockIdx.x & 1) * 64;
    int ct = (blockIdx.x >> 1) * 64;
    int lc = threadIdx.x & 63;
    int lr = threadIdx.x >> 6;
    #pragma unroll
    for (int i = 0; i < 16; i++) {
        int xi = lr + i * 4;
        t[xi][lc] = in[(((size_t)b * BEVH + y) * BEVW + xt + xi) * BEVC + ct + lc];
    }
    __syncthreads();
    #pragma unroll
    for (int i = 0; i < 16; i++) {
        int ci = lr + i * 4;
        out[(((size_t)b * BEVC + ct + ci) * BEVH + y) * BEVW + xt + lc] = t[lc][ci];
    }
}

extern "C" void kernel_launch(void* const* d_in, const int* in_sizes, int n_in,
                              void* d_out, int out_size, void* d_ws, size_t ws_size,
                              hipStream_t stream) {
    const float* feat_maps = (const float*)d_in[0];
    const float* Km        = (const float*)d_in[1];
    const float* Tm        = (const float*)d_in[2];
    const float* trust     = (const float*)d_in[3];
    const float* depths    = (const float*)d_in[4];
    const float* dh_w1     = (const float*)d_in[5];
    const float* dh_b1     = (const float*)d_in[6];
    const float* dh_w2     = (const float*)d_in[7];
    const float* dh_b2     = (const float*)d_in[8];
    const float* fp_w      = (const float*)d_in[9];
    const float* fp_b      = (const float*)d_in[10];
    const float* br_w1     = (const float*)d_in[11];
    const float* br_b1     = (const float*)d_in[12];
    const float* br_w2     = (const float*)d_in[13];
    const float* br_b2     = (const float*)d_in[14];
    float* out = (float*)d_out;

    float* ws  = (float*)d_ws;
    float* h1  = ws;                                     // 12*64*1792 f
    float* dpb = h1 + (size_t)BV * CIN * NPIX;           // 12*1792*32 f
    float* fpb = dpb + (size_t)BV * NPIX * ND;           // 12*1792*128 f
    float* bev = fpb + (size_t)BV * NPIX * BEVC;         // 2*16384*128 f
    float* o2  = bev + (size_t)BQ * BEVH * BEVW * BEVC;  // 2*16384*128 f
    unsigned short* h2b = (unsigned short*)(o2 + (size_t)BQ * BEVH * BEVW * BEVC); // bf16
    unsigned short* wf1 = h2b + (size_t)BQ * BEVH * BEVW * BEVC;                   // 147456 bf16
    unsigned short* wf2 = wf1 + (size_t)9 * 4 * 8 * 64 * 8;

    // weight prep (fragment-linear bf16)
    k_wprep<<<dim3((9 * 4 * 8 * 64 * 8 + 255) / 256), dim3(256), 0, stream>>>(br_w1, wf1);
    k_wprep<<<dim3((9 * 4 * 8 * 64 * 8 + 255) / 256), dim3(256), 0, stream>>>(br_w2, wf2);

    // depth-head conv1 + gelu
    k_conv1<<<dim3(BV * NPIX / 256, CIN / COG), dim3(256), 0, stream>>>(feat_maps, dh_w1, dh_b1, h1);

    // depth probs
    k_depth<<<dim3(BV * NPIX / 256), dim3(256), 0, stream>>>(h1, dh_w2, dh_b2, dpb);

    // feature projection
    k_fp<<<dim3(BV * NPIX * BEVC / 256), dim3(256), 0, stream>>>(feat_maps, fp_w, fp_b, fpb);

    // zero BEV accumulator, scatter
    hipMemsetAsync(bev, 0, (size_t)BQ * BEVH * BEVW * BEVC * sizeof(float), stream);
    k_scatter<<<dim3(BV * NPIX), dim3(BEVC), 0, stream>>>(fpb, dpb, Km, Tm, trust, depths, bev);

    // BEV refinement convs (MFMA): fp32 -> bf16, then bf16 -> fp32
    k_bevconv<0, 1><<<dim3(BEVW / TX2, BEVH / TY2, BQ), dim3(256), 0, stream>>>(bev, wf1, br_b1, h2b);
    k_bevconv<1, 0><<<dim3(BEVW / TX2, BEVH / TY2, BQ), dim3(256), 0, stream>>>(h2b, wf2, br_b2, o2);

    // NHWC -> NCHW
    k_to_nchw<<<dim3(4, BEVH, BQ), dim3(256), 0, stream>>>(o2, out);
}